// Round 1
// baseline (839.589 us; speedup 1.0000x reference)
//
#include <hip/hip_runtime.h>
#include <hip/hip_bf16.h>

// FBANetLayer: Swin-style block. H=W=512, DIM=128, WL=8, SS=4, HEADS=4, HD=32.
// NW=4096 windows x 64 tokens. All GEMMs via mfma_f32_16x16x32_bf16.
// K1: per-window LN1+QKV+attn+proj+residual -> writes x1 into d_out.
// K2: per-64-row LN2+MLP(gelu)+residual, in-place on d_out.

typedef __bf16 bf16x8 __attribute__((ext_vector_type(8)));
typedef float f32x4 __attribute__((ext_vector_type(4)));

#define MFMA16(a, b, c) __builtin_amdgcn_mfma_f32_16x16x32_bf16(a, b, c, 0, 0, 0)

#define SS 4
#define XS 136   // LDS stride (bf16 elems) for 128-wide tiles: 16B-aligned frags, 2-way-conflict only
#define VTS 72   // LDS stride for 64-wide tiles (Vt rows, P rows)
#define HS 264   // LDS stride for 256-wide h tile in MLP

// ws byte offsets (total 458,752 B)
#define QKV_W_OFF 0        // 384x128 bf16
#define PROJ_W_OFF 98304   // 128x128 bf16
#define W1_OFF 131072      // 512x128 bf16
#define W2_OFF 262144      // 128x512 bf16
#define BIAS_OFF 393216    // 4x64x64 f32 rel-pos bias table

__device__ __forceinline__ int regid(int u) { return (u >= 508) ? 2 : ((u >= 504) ? 1 : 0); }

__global__ __launch_bounds__(256) void prep_kernel(
    const float* __restrict__ qkv_w, const float* __restrict__ proj_w,
    const float* __restrict__ w1, const float* __restrict__ w2,
    const float* __restrict__ rel_bias, unsigned char* __restrict__ ws) {
  int tid = blockIdx.x * 256 + threadIdx.x;
  __bf16* qw = (__bf16*)(ws + QKV_W_OFF);
  __bf16* pw = (__bf16*)(ws + PROJ_W_OFF);
  __bf16* w1b = (__bf16*)(ws + W1_OFF);
  __bf16* w2b = (__bf16*)(ws + W2_OFF);
  float* btbl = (float*)(ws + BIAS_OFF);
  if (tid < 49152) qw[tid] = (__bf16)qkv_w[tid];
  if (tid < 16384) pw[tid] = (__bf16)proj_w[tid];
  if (tid < 65536) { w1b[tid] = (__bf16)w1[tid]; w2b[tid] = (__bf16)w2[tid]; }
  if (tid < 16384) {
    int h = tid >> 12, n = (tid >> 6) & 63, m = tid & 63;
    int idx = ((n >> 3) - (m >> 3) + 7) * 15 + ((n & 7) - (m & 7) + 7);
    btbl[tid] = rel_bias[idx * 4 + h];
  }
}

__global__ __launch_bounds__(256) void attn_kernel(
    const float* __restrict__ x, const float* __restrict__ ln1_w, const float* __restrict__ ln1_b,
    const float* __restrict__ qkv_b, const float* __restrict__ proj_b,
    const unsigned char* __restrict__ ws, float* __restrict__ out) {
  __shared__ __bf16 xn[64 * XS];  // LN1 output (A for QKV); reused as attn-out O for proj
  __shared__ __bf16 qs[64 * XS];  // Q (scale folded in)
  __shared__ __bf16 ks[64 * XS];  // K
  __shared__ __bf16 vt[128 * VTS];// V transposed: vt[d][token]
  __shared__ __bf16 ps[64 * VTS]; // softmax P (per-wave private rows)
  __shared__ int rid[64];         // shift-mask region id per token (unrolled coords)

  const int w = blockIdx.x;
  const int wi = w >> 6, wj = w & 63;
  const int tid = threadIdx.x;

  // ---- Phase A: gather rolled rows + LN1 -> bf16 LDS ----
  {
    int n = tid >> 2, q = tid & 3;          // 4 threads per token, 32 elems each
    int r = n >> 3, c = n & 7;
    int io = (wi * 8 + r + SS) & 511;
    int jo = (wj * 8 + c + SS) & 511;
    size_t gid = (size_t)io * 512 + jo;
    const float4* xp = (const float4*)(x + gid * 128 + q * 32);
    float4 xv[8];
    float s = 0.f, s2 = 0.f;
#pragma unroll
    for (int t = 0; t < 8; t++) {
      float4 v = xp[t]; xv[t] = v;
      s += v.x + v.y + v.z + v.w;
      s2 += v.x * v.x + v.y * v.y + v.z * v.z + v.w * v.w;
    }
    s += __shfl_xor(s, 1); s += __shfl_xor(s, 2);
    s2 += __shfl_xor(s2, 1); s2 += __shfl_xor(s2, 2);
    float mean = s * (1.f / 128.f);
    float var = s2 * (1.f / 128.f) - mean * mean;
    float rstd = rsqrtf(var + 1e-5f);
    const float4* wv = (const float4*)(ln1_w + q * 32);
    const float4* bv = (const float4*)(ln1_b + q * 32);
    __bf16* dst = xn + n * XS + q * 32;
#pragma unroll
    for (int t = 0; t < 8; t++) {
      float4 wt = wv[t], bt = bv[t], v = xv[t];
      dst[t * 4 + 0] = (__bf16)((v.x - mean) * rstd * wt.x + bt.x);
      dst[t * 4 + 1] = (__bf16)((v.y - mean) * rstd * wt.y + bt.y);
      dst[t * 4 + 2] = (__bf16)((v.z - mean) * rstd * wt.z + bt.z);
      dst[t * 4 + 3] = (__bf16)((v.w - mean) * rstd * wt.w + bt.w);
    }
    if (q == 0) rid[n] = 3 * regid(wi * 8 + r) + regid(wj * 8 + c);
  }
  __syncthreads();

  const int wid = tid >> 6, lane = tid & 63;
  const int lr = lane & 15, lk = lane >> 4;
  const int r0 = wid * 16;  // this wave's 16 token rows

  // ---- Phase B: QKV = Xn(64x128) @ qkv_w^T(128x384), store q/k/vt bf16 ----
  {
    const __bf16* qw = (const __bf16*)(ws + QKV_W_OFF);
    bf16x8 a[4];
#pragma unroll
    for (int kk = 0; kk < 4; kk++)
      a[kk] = *(const bf16x8*)(xn + (r0 + lr) * XS + kk * 32 + lk * 8);
#pragma unroll
    for (int nt = 0; nt < 24; nt++) {
      f32x4 acc = {0.f, 0.f, 0.f, 0.f};
#pragma unroll
      for (int kk = 0; kk < 4; kk++) {
        bf16x8 b = *(const bf16x8*)(qw + (nt * 16 + lr) * 128 + kk * 32 + lk * 8);
        acc = MFMA16(a[kk], b, acc);
      }
      int j = nt * 16 + lr;
      float bias = qkv_b[j];
      if (nt < 8) {
        const float scale = 0.17677669529663687f;  // 32^-0.5 folded into Q
#pragma unroll
        for (int i = 0; i < 4; i++) qs[(r0 + lk * 4 + i) * XS + j] = (__bf16)((acc[i] + bias) * scale);
      } else if (nt < 16) {
#pragma unroll
        for (int i = 0; i < 4; i++) ks[(r0 + lk * 4 + i) * XS + (j - 128)] = (__bf16)(acc[i] + bias);
      } else {
        int d = j - 256;
#pragma unroll
        for (int i = 0; i < 4; i++) vt[d * VTS + r0 + lk * 4 + i] = (__bf16)(acc[i] + bias);
      }
    }
  }
  __syncthreads();

  // ---- Phase C: per-head scores + softmax + PV ----
  const float* btbl = (const float*)(ws + BIAS_OFF);
  int ridr[4], ridm[4];
#pragma unroll
  for (int i = 0; i < 4; i++) ridr[i] = rid[r0 + lk * 4 + i];
#pragma unroll
  for (int nt = 0; nt < 4; nt++) ridm[nt] = rid[nt * 16 + lr];

  for (int h = 0; h < 4; h++) {
    const f32x4 zero = {0.f, 0.f, 0.f, 0.f};
    bf16x8 aq = *(const bf16x8*)(qs + (r0 + lr) * XS + h * 32 + lk * 8);
    f32x4 sacc[4];
#pragma unroll
    for (int nt = 0; nt < 4; nt++) {
      bf16x8 bk = *(const bf16x8*)(ks + (nt * 16 + lr) * XS + h * 32 + lk * 8);
      sacc[nt] = MFMA16(aq, bk, zero);
    }
    // softmax: lane holds rows r0+lk*4+i, col nt*16+lr; reduce across 16-lane group
#pragma unroll
    for (int i = 0; i < 4; i++) {
      int rr = r0 + lk * 4 + i;
      const float* bt = btbl + h * 4096 + rr * 64;
      float sv[4];
      float mx = -1e30f;
#pragma unroll
      for (int nt = 0; nt < 4; nt++) {
        float v = sacc[nt][i] + bt[nt * 16 + lr];
        if (ridm[nt] != ridr[i]) v -= 100.f;
        sv[nt] = v;
        mx = fmaxf(mx, v);
      }
      mx = fmaxf(mx, __shfl_xor(mx, 1)); mx = fmaxf(mx, __shfl_xor(mx, 2));
      mx = fmaxf(mx, __shfl_xor(mx, 4)); mx = fmaxf(mx, __shfl_xor(mx, 8));
      float sum = 0.f;
#pragma unroll
      for (int nt = 0; nt < 4; nt++) { sv[nt] = __expf(sv[nt] - mx); sum += sv[nt]; }
      sum += __shfl_xor(sum, 1); sum += __shfl_xor(sum, 2);
      sum += __shfl_xor(sum, 4); sum += __shfl_xor(sum, 8);
      float inv = 1.f / sum;
#pragma unroll
      for (int nt = 0; nt < 4; nt++) ps[rr * VTS + nt * 16 + lr] = (__bf16)(sv[nt] * inv);
    }
    __syncthreads();
    // PV: out(16x32) = P(16x64) @ V(64x32)
#pragma unroll
    for (int dt = 0; dt < 2; dt++) {
      f32x4 acc = {0.f, 0.f, 0.f, 0.f};
#pragma unroll
      for (int kk = 0; kk < 2; kk++) {
        bf16x8 ap = *(const bf16x8*)(ps + (r0 + lr) * VTS + kk * 32 + lk * 8);
        bf16x8 bv2 = *(const bf16x8*)(vt + (h * 32 + dt * 16 + lr) * VTS + kk * 32 + lk * 8);
        acc = MFMA16(ap, bv2, acc);
      }
      int d = h * 32 + dt * 16 + lr;
#pragma unroll
      for (int i = 0; i < 4; i++) xn[(r0 + lk * 4 + i) * XS + d] = (__bf16)acc[i];
    }
    __syncthreads();
  }

  // ---- Phase D: proj + residual, scatter back through inverse roll ----
  {
    const __bf16* pw = (const __bf16*)(ws + PROJ_W_OFF);
    bf16x8 ao[4];
#pragma unroll
    for (int kk = 0; kk < 4; kk++)
      ao[kk] = *(const bf16x8*)(xn + (r0 + lr) * XS + kk * 32 + lk * 8);
    size_t gids[4];
#pragma unroll
    for (int i = 0; i < 4; i++) {
      int rr = r0 + lk * 4 + i;
      int io = (wi * 8 + (rr >> 3) + SS) & 511;
      int jo = (wj * 8 + (rr & 7) + SS) & 511;
      gids[i] = (size_t)io * 512 + jo;
    }
#pragma unroll
    for (int nt = 0; nt < 8; nt++) {
      f32x4 acc = {0.f, 0.f, 0.f, 0.f};
#pragma unroll
      for (int kk = 0; kk < 4; kk++) {
        bf16x8 b = *(const bf16x8*)(pw + (nt * 16 + lr) * 128 + kk * 32 + lk * 8);
        acc = MFMA16(ao[kk], b, acc);
      }
      int j = nt * 16 + lr;
      float pb = proj_b[j];
#pragma unroll
      for (int i = 0; i < 4; i++) {
        size_t off = gids[i] * 128 + j;
        out[off] = x[off] + acc[i] + pb;
      }
    }
  }
}

__device__ __forceinline__ float gelu_tanh(float x) {
  float t = 0.7978845608028654f * (x + 0.044715f * x * x * x);
  return 0.5f * x * (1.f + tanhf(t));
}

__global__ __launch_bounds__(256) void mlp_kernel(
    const float* __restrict__ ln2_w, const float* __restrict__ ln2_b,
    const float* __restrict__ mlp_b1, const float* __restrict__ mlp_b2,
    const unsigned char* __restrict__ ws, float* __restrict__ out) {
  __shared__ __bf16 xn[64 * XS];   // LN2 output bf16
  __shared__ __bf16 hb[64 * HS];   // half of h (256 cols), bf16 post-gelu
  const int row0 = blockIdx.x * 64;
  const int tid = threadIdx.x;

  // ---- LN2 on x1 (read from d_out, written by attn_kernel) ----
  {
    int n = tid >> 2, q = tid & 3;
    size_t gid = (size_t)(row0 + n);
    const float4* xp = (const float4*)(out + gid * 128 + q * 32);
    float4 xv[8];
    float s = 0.f, s2 = 0.f;
#pragma unroll
    for (int t = 0; t < 8; t++) {
      float4 v = xp[t]; xv[t] = v;
      s += v.x + v.y + v.z + v.w;
      s2 += v.x * v.x + v.y * v.y + v.z * v.z + v.w * v.w;
    }
    s += __shfl_xor(s, 1); s += __shfl_xor(s, 2);
    s2 += __shfl_xor(s2, 1); s2 += __shfl_xor(s2, 2);
    float mean = s * (1.f / 128.f);
    float var = s2 * (1.f / 128.f) - mean * mean;
    float rstd = rsqrtf(var + 1e-5f);
    const float4* wv = (const float4*)(ln2_w + q * 32);
    const float4* bv = (const float4*)(ln2_b + q * 32);
    __bf16* dst = xn + n * XS + q * 32;
#pragma unroll
    for (int t = 0; t < 8; t++) {
      float4 wt = wv[t], bt = bv[t], v = xv[t];
      dst[t * 4 + 0] = (__bf16)((v.x - mean) * rstd * wt.x + bt.x);
      dst[t * 4 + 1] = (__bf16)((v.y - mean) * rstd * wt.y + bt.y);
      dst[t * 4 + 2] = (__bf16)((v.z - mean) * rstd * wt.z + bt.z);
      dst[t * 4 + 3] = (__bf16)((v.w - mean) * rstd * wt.w + bt.w);
    }
  }
  __syncthreads();

  const int wid = tid >> 6, lane = tid & 63;
  const int lr = lane & 15, lk = lane >> 4;
  const int r0 = wid * 16;
  const __bf16* w1b = (const __bf16*)(ws + W1_OFF);
  const __bf16* w2b = (const __bf16*)(ws + W2_OFF);

  bf16x8 a1[4];
#pragma unroll
  for (int kk = 0; kk < 4; kk++)
    a1[kk] = *(const bf16x8*)(xn + (r0 + lr) * XS + kk * 32 + lk * 8);

  f32x4 macc[8];
#pragma unroll
  for (int t = 0; t < 8; t++) macc[t] = (f32x4){0.f, 0.f, 0.f, 0.f};

  // fc1 (two 256-col halves) -> gelu -> fc2 accumulate
  for (int hh = 0; hh < 2; hh++) {
#pragma unroll
    for (int nt = 0; nt < 16; nt++) {
      f32x4 acc = {0.f, 0.f, 0.f, 0.f};
      int j0 = hh * 256 + nt * 16;
#pragma unroll
      for (int kk = 0; kk < 4; kk++) {
        bf16x8 b = *(const bf16x8*)(w1b + (j0 + lr) * 128 + kk * 32 + lk * 8);
        acc = MFMA16(a1[kk], b, acc);
      }
      float b1v = mlp_b1[j0 + lr];
#pragma unroll
      for (int i = 0; i < 4; i++) {
        float hv = acc[i] + b1v;
        hb[(r0 + lk * 4 + i) * HS + nt * 16 + lr] = (__bf16)gelu_tanh(hv);
      }
    }
    __syncthreads();
#pragma unroll
    for (int kk2 = 0; kk2 < 8; kk2++) {
      bf16x8 ah = *(const bf16x8*)(hb + (r0 + lr) * HS + kk2 * 32 + lk * 8);
#pragma unroll
      for (int nt2 = 0; nt2 < 8; nt2++) {
        bf16x8 b = *(const bf16x8*)(w2b + (nt2 * 16 + lr) * 512 + hh * 256 + kk2 * 32 + lk * 8);
        macc[nt2] = MFMA16(ah, b, macc[nt2]);
      }
    }
    __syncthreads();
  }

  // epilogue: out = x1 + fc2 + b2 (in place)
#pragma unroll
  for (int nt2 = 0; nt2 < 8; nt2++) {
    int j = nt2 * 16 + lr;
    float b2 = mlp_b2[j];
#pragma unroll
    for (int i = 0; i < 4; i++) {
      size_t off = (size_t)(row0 + r0 + lk * 4 + i) * 128 + j;
      out[off] = out[off] + macc[nt2][i] + b2;
    }
  }
}

extern "C" void kernel_launch(void* const* d_in, const int* in_sizes, int n_in,
                              void* d_out, int out_size, void* d_ws, size_t ws_size,
                              hipStream_t stream) {
  const float* x      = (const float*)d_in[0];
  const float* ln1_w  = (const float*)d_in[1];
  const float* ln1_b  = (const float*)d_in[2];
  const float* qkv_w  = (const float*)d_in[3];
  const float* qkv_b  = (const float*)d_in[4];
  const float* rel_b  = (const float*)d_in[5];
  const float* proj_w = (const float*)d_in[6];
  const float* proj_b = (const float*)d_in[7];
  const float* ln2_w  = (const float*)d_in[8];
  const float* ln2_b  = (const float*)d_in[9];
  const float* mlp_w1 = (const float*)d_in[10];
  const float* mlp_b1 = (const float*)d_in[11];
  const float* mlp_w2 = (const float*)d_in[12];
  const float* mlp_b2 = (const float*)d_in[13];
  float* out = (float*)d_out;
  unsigned char* ws = (unsigned char*)d_ws;

  prep_kernel<<<256, 256, 0, stream>>>(qkv_w, proj_w, mlp_w1, mlp_w2, rel_b, ws);
  attn_kernel<<<4096, 256, 0, stream>>>(x, ln1_w, ln1_b, qkv_b, proj_b, ws, out);
  mlp_kernel<<<4096, 256, 0, stream>>>(ln2_w, ln2_b, mlp_b1, mlp_b2, ws, out);
}

// Round 2
// 412.627 us; speedup vs baseline: 2.0347x; 2.0347x over previous
//
#include <hip/hip_runtime.h>
#include <hip/hip_bf16.h>

// FBANetLayer: Swin-style block. H=W=512, DIM=128, WL=8, SS=4, HEADS=4, HD=32.
// K1 attn: per-window LN1+QKV+attn+proj+residual -> x1 into d_out.
//   Waves own COLUMN slices of QKV/proj; B-frags register-resident, hoisted.
// K2 mlp: 128 rows/block, weights chunk-staged in LDS (XOR-swizzled), fc2
//   accumulated across 4 hidden chunks.

typedef __bf16 bf16x8 __attribute__((ext_vector_type(8)));
typedef float f32x4 __attribute__((ext_vector_type(4)));

#define MFMA16(a, b, c) __builtin_amdgcn_mfma_f32_16x16x32_bf16(a, b, c, 0, 0, 0)

#define SS 4
#define XS 136   // LDS stride (bf16) for 128-wide tiles
#define VTS 72   // LDS stride for 64-wide tiles

// ws byte offsets
#define QKV_W_OFF 0        // 384x128 bf16 (plain)
#define PROJ_W_OFF 98304   // 128x128 bf16 (plain)
#define W1_OFF 131072      // 4 chunks x [128][128] bf16, XOR-swizzled rows
#define W2_OFF 262144      // 4 chunks x [128][128] bf16, XOR-swizzled rows
#define BIAS_OFF 393216    // 4x64x64 f32 rel-pos bias table

__device__ __forceinline__ int regid(int u) { return (u >= 508) ? 2 : ((u >= 504) ? 1 : 0); }

__global__ __launch_bounds__(256) void prep_kernel(
    const float* __restrict__ qkv_w, const float* __restrict__ proj_w,
    const float* __restrict__ w1, const float* __restrict__ w2,
    const float* __restrict__ rel_bias, unsigned char* __restrict__ ws) {
  int tid = blockIdx.x * 256 + threadIdx.x;
  __bf16* qw = (__bf16*)(ws + QKV_W_OFF);
  __bf16* pw = (__bf16*)(ws + PROJ_W_OFF);
  __bf16* w1b = (__bf16*)(ws + W1_OFF);
  __bf16* w2b = (__bf16*)(ws + W2_OFF);
  float* btbl = (float*)(ws + BIAS_OFF);
  if (tid < 49152) qw[tid] = (__bf16)qkv_w[tid];
  if (tid < 16384) pw[tid] = (__bf16)proj_w[tid];
  if (tid < 65536) {
    // w1[j][k], j=0..511,k=0..127 -> chunk c=j>>7, tile row r=j&127.
    // swizzle: slot(k>>3) ^= (r&15); 16B slots within 256B row.
    int j = tid >> 7, k = tid & 127;
    int c = j >> 7, r = j & 127;
    int s2 = (k >> 3) ^ (r & 15);
    w1b[c * 16384 + r * 128 + s2 * 8 + (k & 7)] = (__bf16)w1[tid];
    // w2[j][k], j=0..127,k=0..511 -> chunk c=k>>7 (K chunking), row j.
    int j2 = tid >> 9, k2 = tid & 511;
    int c2 = k2 >> 7, kc = k2 & 127;
    int s3 = (kc >> 3) ^ (j2 & 15);
    w2b[c2 * 16384 + j2 * 128 + s3 * 8 + (kc & 7)] = (__bf16)w2[tid];
  }
  if (tid < 16384) {
    int h = tid >> 12, n = (tid >> 6) & 63, m = tid & 63;
    int idx = ((n >> 3) - (m >> 3) + 7) * 15 + ((n & 7) - (m & 7) + 7);
    btbl[tid] = rel_bias[idx * 4 + h];
  }
}

__global__ __launch_bounds__(256, 2) void attn_kernel(
    const float* __restrict__ x, const float* __restrict__ ln1_w, const float* __restrict__ ln1_b,
    const float* __restrict__ qkv_b, const float* __restrict__ proj_b,
    const unsigned char* __restrict__ ws, float* __restrict__ out) {
  __shared__ __attribute__((aligned(16))) __bf16 xn[64 * XS];  // LN1 out; reused as attn-out O
  __shared__ __attribute__((aligned(16))) __bf16 qs[64 * XS];
  __shared__ __attribute__((aligned(16))) __bf16 ks[64 * XS];
  __shared__ __attribute__((aligned(16))) __bf16 vt[128 * VTS]; // V transposed
  __shared__ __attribute__((aligned(16))) __bf16 ps[64 * VTS];
  __shared__ int rid[64];

  const int w = blockIdx.x;
  const int wi = w >> 6, wj = w & 63;
  const int tid = threadIdx.x;
  const int wid = tid >> 6, lane = tid & 63;
  const int lr = lane & 15, lk = lane >> 4;
  const int r0 = wid * 16;

  // ---- Hoisted: QKV B-frags (col-slice wid*96..wid*96+95) into registers ----
  const __bf16* qw = (const __bf16*)(ws + QKV_W_OFF);
  bf16x8 bw[6][4];
  float qb[6];
#pragma unroll
  for (int nt = 0; nt < 6; nt++) {
    int j = wid * 96 + nt * 16 + lr;
    qb[nt] = qkv_b[j];
#pragma unroll
    for (int kk = 0; kk < 4; kk++)
      bw[nt][kk] = *(const bf16x8*)(qw + j * 128 + kk * 32 + lk * 8);
  }

  // ---- Phase A: gather rolled rows + LN1 -> bf16 LDS ----
  {
    int n = tid >> 2, q = tid & 3;
    int r = n >> 3, c = n & 7;
    int io = (wi * 8 + r + SS) & 511;
    int jo = (wj * 8 + c + SS) & 511;
    size_t gid = (size_t)io * 512 + jo;
    const float4* xp = (const float4*)(x + gid * 128 + q * 32);
    float4 xv[8];
    float s = 0.f, s2 = 0.f;
#pragma unroll
    for (int t = 0; t < 8; t++) {
      float4 v = xp[t]; xv[t] = v;
      s += v.x + v.y + v.z + v.w;
      s2 += v.x * v.x + v.y * v.y + v.z * v.z + v.w * v.w;
    }
    s += __shfl_xor(s, 1); s += __shfl_xor(s, 2);
    s2 += __shfl_xor(s2, 1); s2 += __shfl_xor(s2, 2);
    float mean = s * (1.f / 128.f);
    float var = s2 * (1.f / 128.f) - mean * mean;
    float rstd = rsqrtf(var + 1e-5f);
    const float4* wv = (const float4*)(ln1_w + q * 32);
    const float4* bv = (const float4*)(ln1_b + q * 32);
    __bf16* dst = xn + n * XS + q * 32;
#pragma unroll
    for (int t = 0; t < 8; t++) {
      float4 wt = wv[t], bt = bv[t], v = xv[t];
      dst[t * 4 + 0] = (__bf16)((v.x - mean) * rstd * wt.x + bt.x);
      dst[t * 4 + 1] = (__bf16)((v.y - mean) * rstd * wt.y + bt.y);
      dst[t * 4 + 2] = (__bf16)((v.z - mean) * rstd * wt.z + bt.z);
      dst[t * 4 + 3] = (__bf16)((v.w - mean) * rstd * wt.w + bt.w);
    }
    if (q == 0) rid[n] = 3 * regid(wi * 8 + r) + regid(wj * 8 + c);
  }
  __syncthreads();

  // ---- Phase B: QKV col-slice; each wave computes its 96 cols for ALL 64 rows ----
  {
    const float scale = 0.17677669529663687f;
#pragma unroll
    for (int st = 0; st < 4; st++) {
      bf16x8 a[4];
#pragma unroll
      for (int kk = 0; kk < 4; kk++)
        a[kk] = *(const bf16x8*)(xn + (st * 16 + lr) * XS + kk * 32 + lk * 8);
#pragma unroll
      for (int nt = 0; nt < 6; nt++) {
        f32x4 acc = {0.f, 0.f, 0.f, 0.f};
#pragma unroll
        for (int kk = 0; kk < 4; kk++) acc = MFMA16(a[kk], bw[nt][kk], acc);
        int j = wid * 96 + nt * 16 + lr;
        float bias = qb[nt];
        if (j < 128) {
#pragma unroll
          for (int i = 0; i < 4; i++)
            qs[(st * 16 + lk * 4 + i) * XS + j] = (__bf16)((acc[i] + bias) * scale);
        } else if (j < 256) {
#pragma unroll
          for (int i = 0; i < 4; i++)
            ks[(st * 16 + lk * 4 + i) * XS + (j - 128)] = (__bf16)(acc[i] + bias);
        } else {
          int d = j - 256;
#pragma unroll
          for (int i = 0; i < 4; i++)
            vt[d * VTS + st * 16 + lk * 4 + i] = (__bf16)(acc[i] + bias);
        }
      }
    }
  }
  __syncthreads();

  // ---- Phase C: per-head scores + softmax + PV (wave owns rows r0..r0+15) ----
  const float* btbl = (const float*)(ws + BIAS_OFF);
  int ridr[4], ridm[4];
#pragma unroll
  for (int i = 0; i < 4; i++) ridr[i] = rid[r0 + lk * 4 + i];
#pragma unroll
  for (int nt = 0; nt < 4; nt++) ridm[nt] = rid[nt * 16 + lr];

#pragma unroll
  for (int h = 0; h < 4; h++) {
    float bias_r[4][4];
#pragma unroll
    for (int i = 0; i < 4; i++)
#pragma unroll
      for (int nt = 0; nt < 4; nt++)
        bias_r[i][nt] = btbl[h * 4096 + (r0 + lk * 4 + i) * 64 + nt * 16 + lr];
    const f32x4 zero = {0.f, 0.f, 0.f, 0.f};
    bf16x8 aq = *(const bf16x8*)(qs + (r0 + lr) * XS + h * 32 + lk * 8);
    f32x4 sacc[4];
#pragma unroll
    for (int nt = 0; nt < 4; nt++) {
      bf16x8 bk = *(const bf16x8*)(ks + (nt * 16 + lr) * XS + h * 32 + lk * 8);
      sacc[nt] = MFMA16(aq, bk, zero);
    }
#pragma unroll
    for (int i = 0; i < 4; i++) {
      int rr = r0 + lk * 4 + i;
      float sv[4];
      float mx = -1e30f;
#pragma unroll
      for (int nt = 0; nt < 4; nt++) {
        float v = sacc[nt][i] + bias_r[i][nt];
        if (ridm[nt] != ridr[i]) v -= 100.f;
        sv[nt] = v;
        mx = fmaxf(mx, v);
      }
      mx = fmaxf(mx, __shfl_xor(mx, 1)); mx = fmaxf(mx, __shfl_xor(mx, 2));
      mx = fmaxf(mx, __shfl_xor(mx, 4)); mx = fmaxf(mx, __shfl_xor(mx, 8));
      float sum = 0.f;
#pragma unroll
      for (int nt = 0; nt < 4; nt++) { sv[nt] = __expf(sv[nt] - mx); sum += sv[nt]; }
      sum += __shfl_xor(sum, 1); sum += __shfl_xor(sum, 2);
      sum += __shfl_xor(sum, 4); sum += __shfl_xor(sum, 8);
      float inv = 1.f / sum;
#pragma unroll
      for (int nt = 0; nt < 4; nt++) ps[rr * VTS + nt * 16 + lr] = (__bf16)(sv[nt] * inv);
    }
    // same-wave LDS write->read: drain lgkm before PV reads other lanes' P rows
    asm volatile("s_waitcnt lgkmcnt(0)" ::: "memory");
#pragma unroll
    for (int dt = 0; dt < 2; dt++) {
      f32x4 acc = {0.f, 0.f, 0.f, 0.f};
#pragma unroll
      for (int kk = 0; kk < 2; kk++) {
        bf16x8 ap = *(const bf16x8*)(ps + (r0 + lr) * VTS + kk * 32 + lk * 8);
        bf16x8 bv2 = *(const bf16x8*)(vt + (h * 32 + dt * 16 + lr) * VTS + kk * 32 + lk * 8);
        acc = MFMA16(ap, bv2, acc);
      }
      int d = h * 32 + dt * 16 + lr;
#pragma unroll
      for (int i = 0; i < 4; i++) xn[(r0 + lk * 4 + i) * XS + d] = (__bf16)acc[i];
    }
    // P rows are rewritten next head: ensure PV reads retired first
    asm volatile("s_waitcnt lgkmcnt(0)" ::: "memory");
  }
  __syncthreads();

  // ---- Phase D: proj col-slice (wave owns 32 cols) + residual, inverse roll ----
  {
    const __bf16* pw = (const __bf16*)(ws + PROJ_W_OFF);
    bf16x8 pwf[2][4];
    float pb2[2];
#pragma unroll
    for (int nt2 = 0; nt2 < 2; nt2++) {
      int j = wid * 32 + nt2 * 16 + lr;
      pb2[nt2] = proj_b[j];
#pragma unroll
      for (int kk = 0; kk < 4; kk++)
        pwf[nt2][kk] = *(const bf16x8*)(pw + j * 128 + kk * 32 + lk * 8);
    }
#pragma unroll
    for (int st = 0; st < 4; st++) {
      bf16x8 ao[4];
#pragma unroll
      for (int kk = 0; kk < 4; kk++)
        ao[kk] = *(const bf16x8*)(xn + (st * 16 + lr) * XS + kk * 32 + lk * 8);
      size_t gids[4];
#pragma unroll
      for (int i = 0; i < 4; i++) {
        int rr = st * 16 + lk * 4 + i;
        int io = (wi * 8 + (rr >> 3) + SS) & 511;
        int jo = (wj * 8 + (rr & 7) + SS) & 511;
        gids[i] = (size_t)io * 512 + jo;
      }
#pragma unroll
      for (int nt2 = 0; nt2 < 2; nt2++) {
        f32x4 acc = {0.f, 0.f, 0.f, 0.f};
#pragma unroll
        for (int kk = 0; kk < 4; kk++) acc = MFMA16(ao[kk], pwf[nt2][kk], acc);
        int j = wid * 32 + nt2 * 16 + lr;
#pragma unroll
        for (int i = 0; i < 4; i++) {
          size_t off = gids[i] * 128 + j;
          out[off] = x[off] + acc[i] + pb2[nt2];
        }
      }
    }
  }
}

__device__ __forceinline__ float gelu_tanh(float x) {
  float t = 0.7978845608028654f * (x + 0.044715f * x * x * x);
  return 0.5f * x * (1.f + tanhf(t));
}

__global__ __launch_bounds__(512) void mlp_kernel(
    const float* __restrict__ ln2_w, const float* __restrict__ ln2_b,
    const float* __restrict__ mlp_b1, const float* __restrict__ mlp_b2,
    const unsigned char* __restrict__ ws, float* __restrict__ out) {
  __shared__ __attribute__((aligned(16))) __bf16 xn[128 * XS];   // LN2 out bf16
  __shared__ __attribute__((aligned(16))) __bf16 hb[128 * XS];   // gelu(h) chunk bf16
  __shared__ __attribute__((aligned(16))) __bf16 w1c[128 * 128]; // w1 chunk (swizzled rows)
  __shared__ __attribute__((aligned(16))) __bf16 w2c[128 * 128]; // w2 chunk (swizzled rows)
  const int row0 = blockIdx.x * 128;
  const int tid = threadIdx.x;

  // ---- LN2 on x1 (128 rows, 512 threads: 4 per token) ----
  {
    int n = tid >> 2, q = tid & 3;
    const float4* xp = (const float4*)(out + (size_t)(row0 + n) * 128 + q * 32);
    float4 xv[8];
    float s = 0.f, s2 = 0.f;
#pragma unroll
    for (int t = 0; t < 8; t++) {
      float4 v = xp[t]; xv[t] = v;
      s += v.x + v.y + v.z + v.w;
      s2 += v.x * v.x + v.y * v.y + v.z * v.z + v.w * v.w;
    }
    s += __shfl_xor(s, 1); s += __shfl_xor(s, 2);
    s2 += __shfl_xor(s2, 1); s2 += __shfl_xor(s2, 2);
    float mean = s * (1.f / 128.f);
    float var = s2 * (1.f / 128.f) - mean * mean;
    float rstd = rsqrtf(var + 1e-5f);
    const float4* wv = (const float4*)(ln2_w + q * 32);
    const float4* bv = (const float4*)(ln2_b + q * 32);
    __bf16* dst = xn + n * XS + q * 32;
#pragma unroll
    for (int t = 0; t < 8; t++) {
      float4 wt = wv[t], bt = bv[t], v = xv[t];
      dst[t * 4 + 0] = (__bf16)((v.x - mean) * rstd * wt.x + bt.x);
      dst[t * 4 + 1] = (__bf16)((v.y - mean) * rstd * wt.y + bt.y);
      dst[t * 4 + 2] = (__bf16)((v.z - mean) * rstd * wt.z + bt.z);
      dst[t * 4 + 3] = (__bf16)((v.w - mean) * rstd * wt.w + bt.w);
    }
  }
  __syncthreads();

  const int wid = tid >> 6, lane = tid & 63;
  const int lr = lane & 15, lk = lane >> 4;
  const int r0 = wid * 16;  // 8 waves x 16 rows = 128

  bf16x8 a1[4];
#pragma unroll
  for (int kk = 0; kk < 4; kk++)
    a1[kk] = *(const bf16x8*)(xn + (r0 + lr) * XS + kk * 32 + lk * 8);

  f32x4 macc[8];
#pragma unroll
  for (int t = 0; t < 8; t++) macc[t] = (f32x4){0.f, 0.f, 0.f, 0.f};

  const float4* w1src = (const float4*)(ws + W1_OFF);
  const float4* w2src = (const float4*)(ws + W2_OFF);

  for (int c = 0; c < 4; c++) {
    // stage weight chunks (32 KB each) into LDS
    float4* w1d = (float4*)w1c;
    float4* w2d = (float4*)w2c;
#pragma unroll
    for (int t = 0; t < 4; t++) {
      int idx = tid + t * 512;
      w1d[idx] = w1src[c * 2048 + idx];
      w2d[idx] = w2src[c * 2048 + idx];
    }
    __syncthreads();

    // fc1: h[:, c*128..] = gelu(xn @ w1c^T + b1)
#pragma unroll
    for (int nt = 0; nt < 8; nt++) {
      f32x4 acc = {0.f, 0.f, 0.f, 0.f};
#pragma unroll
      for (int kk = 0; kk < 4; kk++) {
        bf16x8 b = *(const bf16x8*)(w1c + (nt * 16 + lr) * 128 + (((kk * 4 + lk) ^ lr) << 3));
        acc = MFMA16(a1[kk], b, acc);
      }
      float b1v = mlp_b1[c * 128 + nt * 16 + lr];
#pragma unroll
      for (int i = 0; i < 4; i++)
        hb[(r0 + lk * 4 + i) * XS + nt * 16 + lr] = (__bf16)gelu_tanh(acc[i] + b1v);
    }
    __syncthreads();

    // fc2 partial: macc += h_chunk @ w2c^T
    bf16x8 ah[4];
#pragma unroll
    for (int kk = 0; kk < 4; kk++)
      ah[kk] = *(const bf16x8*)(hb + (r0 + lr) * XS + kk * 32 + lk * 8);
#pragma unroll
    for (int nt2 = 0; nt2 < 8; nt2++) {
#pragma unroll
      for (int kk = 0; kk < 4; kk++) {
        bf16x8 b = *(const bf16x8*)(w2c + (nt2 * 16 + lr) * 128 + (((kk * 4 + lk) ^ lr) << 3));
        macc[nt2] = MFMA16(ah[kk], b, macc[nt2]);
      }
    }
    __syncthreads();
  }

  // epilogue: out = x1 + fc2 + b2 (in place)
#pragma unroll
  for (int nt2 = 0; nt2 < 8; nt2++) {
    int j = nt2 * 16 + lr;
    float b2 = mlp_b2[j];
#pragma unroll
    for (int i = 0; i < 4; i++) {
      size_t off = (size_t)(row0 + r0 + lk * 4 + i) * 128 + j;
      out[off] = out[off] + macc[nt2][i] + b2;
    }
  }
}

extern "C" void kernel_launch(void* const* d_in, const int* in_sizes, int n_in,
                              void* d_out, int out_size, void* d_ws, size_t ws_size,
                              hipStream_t stream) {
  const float* x      = (const float*)d_in[0];
  const float* ln1_w  = (const float*)d_in[1];
  const float* ln1_b  = (const float*)d_in[2];
  const float* qkv_w  = (const float*)d_in[3];
  const float* qkv_b  = (const float*)d_in[4];
  const float* rel_b  = (const float*)d_in[5];
  const float* proj_w = (const float*)d_in[6];
  const float* proj_b = (const float*)d_in[7];
  const float* ln2_w  = (const float*)d_in[8];
  const float* ln2_b  = (const float*)d_in[9];
  const float* mlp_w1 = (const float*)d_in[10];
  const float* mlp_b1 = (const float*)d_in[11];
  const float* mlp_w2 = (const float*)d_in[12];
  const float* mlp_b2 = (const float*)d_in[13];
  float* out = (float*)d_out;
  unsigned char* ws = (unsigned char*)d_ws;

  prep_kernel<<<256, 256, 0, stream>>>(qkv_w, proj_w, mlp_w1, mlp_w2, rel_b, ws);
  attn_kernel<<<4096, 256, 0, stream>>>(x, ln1_w, ln1_b, qkv_b, proj_b, ws, out);
  mlp_kernel<<<2048, 512, 0, stream>>>(ln2_w, ln2_b, mlp_b1, mlp_b2, ws, out);
}

// Round 3
// 306.421 us; speedup vs baseline: 2.7400x; 1.3466x over previous
//
#include <hip/hip_runtime.h>
#include <hip/hip_bf16.h>

// FBANetLayer: Swin-style block. H=W=512, DIM=128, WL=8, SS=4, HEADS=4, HD=32.
// prep: weights -> bf16 in MFMA-frag order ([wave][tile][kk][lane][8]); bias table.
// attn: per-window LN1+QKV+attn+proj+residual -> x1 into d_out. Col-slice waves,
//       register-resident B-frags (coalesced frag-order loads).
// mlp:  1024 blocks x 4 row-tiles(64). Weights fully register-resident per wave
//       (fc1 64-col slice, fc2 16-col slice). hb/xn XOR-swizzled. 2 barriers/tile.

typedef __bf16 bf16x8 __attribute__((ext_vector_type(8)));
typedef float f32x4 __attribute__((ext_vector_type(4)));

#define MFMA16(a, b, c) __builtin_amdgcn_mfma_f32_16x16x32_bf16(a, b, c, 0, 0, 0)

#define SS 4
#define XS 136   // attn LDS stride (bf16) for 128-wide tiles
#define VTS 72   // attn LDS stride for 64-wide tiles

// ws byte offsets (total 458,752 B)
#define QKV_W_OFF 0        // 384x128 bf16, frag order: ((wid*6+nt)*4+kk)*512 + lane*8
#define PROJ_W_OFF 98304   // 128x128 bf16, frag order: ((wid*2+nt2)*4+kk)*512 + lane*8
#define W1_OFF 131072      // 512x128 bf16, frag order: ((wid*4+nt)*4+kk)*512 + lane*8
#define W2_OFF 262144      // 128x512 bf16, frag order: (wid*16+kk)*512 + lane*8
#define BIAS_OFF 393216    // 4x64x64 f32 rel-pos bias table

__device__ __forceinline__ int regid(int u) { return (u >= 508) ? 2 : ((u >= 504) ? 1 : 0); }

__global__ __launch_bounds__(256) void prep_kernel(
    const float* __restrict__ qkv_w, const float* __restrict__ proj_w,
    const float* __restrict__ w1, const float* __restrict__ w2,
    const float* __restrict__ rel_bias, unsigned char* __restrict__ ws) {
  int tid = blockIdx.x * 256 + threadIdx.x;
  __bf16* qw = (__bf16*)(ws + QKV_W_OFF);
  __bf16* pw = (__bf16*)(ws + PROJ_W_OFF);
  __bf16* w1b = (__bf16*)(ws + W1_OFF);
  __bf16* w2b = (__bf16*)(ws + W2_OFF);
  float* btbl = (float*)(ws + BIAS_OFF);
  if (tid < 49152) {
    int e = tid & 7, lane = (tid >> 3) & 63, kk = (tid >> 9) & 3;
    int f = tid >> 11;            // 0..23 = wid*6+nt
    int wid = f / 6, nt = f % 6;
    int j = wid * 96 + nt * 16 + (lane & 15);
    int k = kk * 32 + (lane >> 4) * 8 + e;
    qw[tid] = (__bf16)qkv_w[j * 128 + k];
  }
  if (tid < 16384) {
    int e = tid & 7, lane = (tid >> 3) & 63, kk = (tid >> 9) & 3;
    int nt2 = (tid >> 11) & 1, wid = (tid >> 12) & 3;
    int j = wid * 32 + nt2 * 16 + (lane & 15);
    int k = kk * 32 + (lane >> 4) * 8 + e;
    pw[tid] = (__bf16)proj_w[j * 128 + k];
  }
  if (tid < 65536) {
    { int e = tid & 7, lane = (tid >> 3) & 63, kk = (tid >> 9) & 3;
      int nt = (tid >> 11) & 3, wid = (tid >> 13) & 7;
      int j = wid * 64 + nt * 16 + (lane & 15);
      int k = kk * 32 + (lane >> 4) * 8 + e;
      w1b[tid] = (__bf16)w1[j * 128 + k]; }
    { int e = tid & 7, lane = (tid >> 3) & 63, kk = (tid >> 9) & 15, wid = (tid >> 13) & 7;
      int j = wid * 16 + (lane & 15);
      int k = kk * 32 + (lane >> 4) * 8 + e;
      w2b[tid] = (__bf16)w2[j * 512 + k]; }
  }
  if (tid < 16384) {
    int h = tid >> 12, n = (tid >> 6) & 63, m = tid & 63;
    int idx = ((n >> 3) - (m >> 3) + 7) * 15 + ((n & 7) - (m & 7) + 7);
    btbl[tid] = rel_bias[idx * 4 + h];
  }
}

__global__ __launch_bounds__(256, 2) void attn_kernel(
    const float* __restrict__ x, const float* __restrict__ ln1_w, const float* __restrict__ ln1_b,
    const float* __restrict__ qkv_b, const float* __restrict__ proj_b,
    const unsigned char* __restrict__ ws, float* __restrict__ out) {
  __shared__ __attribute__((aligned(16))) __bf16 xn[64 * XS];  // LN1 out; reused as attn-out O
  __shared__ __attribute__((aligned(16))) __bf16 qs[64 * XS];
  __shared__ __attribute__((aligned(16))) __bf16 ks[64 * XS];
  __shared__ __attribute__((aligned(16))) __bf16 vt[128 * VTS]; // V transposed
  __shared__ __attribute__((aligned(16))) __bf16 ps[64 * VTS];
  __shared__ int rid[64];

  const int w = blockIdx.x;
  const int wi = w >> 6, wj = w & 63;
  const int tid = threadIdx.x;
  const int wid = tid >> 6, lane = tid & 63;
  const int lr = lane & 15, lk = lane >> 4;
  const int r0 = wid * 16;

  // ---- Hoisted: QKV B-frags (col-slice wid*96..+95), coalesced frag-order ----
  const __bf16* qw = (const __bf16*)(ws + QKV_W_OFF);
  bf16x8 bw[6][4];
  float qb[6];
#pragma unroll
  for (int nt = 0; nt < 6; nt++) {
    qb[nt] = qkv_b[wid * 96 + nt * 16 + lr];
#pragma unroll
    for (int kk = 0; kk < 4; kk++)
      bw[nt][kk] = *(const bf16x8*)(qw + ((wid * 6 + nt) * 4 + kk) * 512 + lane * 8);
  }

  // ---- Phase A: gather rolled rows + LN1 -> bf16 LDS ----
  {
    int n = tid >> 2, q = tid & 3;
    int r = n >> 3, c = n & 7;
    int io = (wi * 8 + r + SS) & 511;
    int jo = (wj * 8 + c + SS) & 511;
    size_t gid = (size_t)io * 512 + jo;
    const float4* xp = (const float4*)(x + gid * 128 + q * 32);
    float4 xv[8];
    float s = 0.f, s2 = 0.f;
#pragma unroll
    for (int t = 0; t < 8; t++) {
      float4 v = xp[t]; xv[t] = v;
      s += v.x + v.y + v.z + v.w;
      s2 += v.x * v.x + v.y * v.y + v.z * v.z + v.w * v.w;
    }
    s += __shfl_xor(s, 1); s += __shfl_xor(s, 2);
    s2 += __shfl_xor(s2, 1); s2 += __shfl_xor(s2, 2);
    float mean = s * (1.f / 128.f);
    float var = s2 * (1.f / 128.f) - mean * mean;
    float rstd = rsqrtf(var + 1e-5f);
    const float4* wv = (const float4*)(ln1_w + q * 32);
    const float4* bv = (const float4*)(ln1_b + q * 32);
    __bf16* dst = xn + n * XS + q * 32;
#pragma unroll
    for (int t = 0; t < 8; t++) {
      float4 wt = wv[t], bt = bv[t], v = xv[t];
      dst[t * 4 + 0] = (__bf16)((v.x - mean) * rstd * wt.x + bt.x);
      dst[t * 4 + 1] = (__bf16)((v.y - mean) * rstd * wt.y + bt.y);
      dst[t * 4 + 2] = (__bf16)((v.z - mean) * rstd * wt.z + bt.z);
      dst[t * 4 + 3] = (__bf16)((v.w - mean) * rstd * wt.w + bt.w);
    }
    if (q == 0) rid[n] = 3 * regid(wi * 8 + r) + regid(wj * 8 + c);
  }
  __syncthreads();

  // ---- Phase B: QKV col-slice; each wave computes its 96 cols for ALL 64 rows ----
  {
    const float scale = 0.17677669529663687f;
#pragma unroll
    for (int st = 0; st < 4; st++) {
      bf16x8 a[4];
#pragma unroll
      for (int kk = 0; kk < 4; kk++)
        a[kk] = *(const bf16x8*)(xn + (st * 16 + lr) * XS + kk * 32 + lk * 8);
#pragma unroll
      for (int nt = 0; nt < 6; nt++) {
        f32x4 acc = {0.f, 0.f, 0.f, 0.f};
#pragma unroll
        for (int kk = 0; kk < 4; kk++) acc = MFMA16(a[kk], bw[nt][kk], acc);
        int j = wid * 96 + nt * 16 + lr;
        float bias = qb[nt];
        if (j < 128) {
#pragma unroll
          for (int i = 0; i < 4; i++)
            qs[(st * 16 + lk * 4 + i) * XS + j] = (__bf16)((acc[i] + bias) * scale);
        } else if (j < 256) {
#pragma unroll
          for (int i = 0; i < 4; i++)
            ks[(st * 16 + lk * 4 + i) * XS + (j - 128)] = (__bf16)(acc[i] + bias);
        } else {
          int d = j - 256;
#pragma unroll
          for (int i = 0; i < 4; i++)
            vt[d * VTS + st * 16 + lk * 4 + i] = (__bf16)(acc[i] + bias);
        }
      }
    }
  }
  __syncthreads();

  // ---- hoist proj B-frags: loads overlap Phase C compute ----
  const __bf16* pw = (const __bf16*)(ws + PROJ_W_OFF);
  bf16x8 pwf[2][4];
  float pb2[2];
#pragma unroll
  for (int nt2 = 0; nt2 < 2; nt2++) {
    pb2[nt2] = proj_b[wid * 32 + nt2 * 16 + lr];
#pragma unroll
    for (int kk = 0; kk < 4; kk++)
      pwf[nt2][kk] = *(const bf16x8*)(pw + ((wid * 2 + nt2) * 4 + kk) * 512 + lane * 8);
  }

  // ---- Phase C: per-head scores + softmax + PV (wave owns rows r0..r0+15) ----
  const float* btbl = (const float*)(ws + BIAS_OFF);
  int ridr[4], ridm[4];
#pragma unroll
  for (int i = 0; i < 4; i++) ridr[i] = rid[r0 + lk * 4 + i];
#pragma unroll
  for (int nt = 0; nt < 4; nt++) ridm[nt] = rid[nt * 16 + lr];

#pragma unroll
  for (int h = 0; h < 4; h++) {
    float bias_r[4][4];
#pragma unroll
    for (int i = 0; i < 4; i++)
#pragma unroll
      for (int nt = 0; nt < 4; nt++)
        bias_r[i][nt] = btbl[h * 4096 + (r0 + lk * 4 + i) * 64 + nt * 16 + lr];
    const f32x4 zero = {0.f, 0.f, 0.f, 0.f};
    bf16x8 aq = *(const bf16x8*)(qs + (r0 + lr) * XS + h * 32 + lk * 8);
    f32x4 sacc[4];
#pragma unroll
    for (int nt = 0; nt < 4; nt++) {
      bf16x8 bk = *(const bf16x8*)(ks + (nt * 16 + lr) * XS + h * 32 + lk * 8);
      sacc[nt] = MFMA16(aq, bk, zero);
    }
#pragma unroll
    for (int i = 0; i < 4; i++) {
      int rr = r0 + lk * 4 + i;
      float sv[4];
      float mx = -1e30f;
#pragma unroll
      for (int nt = 0; nt < 4; nt++) {
        float v = sacc[nt][i] + bias_r[i][nt];
        if (ridm[nt] != ridr[i]) v -= 100.f;
        sv[nt] = v;
        mx = fmaxf(mx, v);
      }
      mx = fmaxf(mx, __shfl_xor(mx, 1)); mx = fmaxf(mx, __shfl_xor(mx, 2));
      mx = fmaxf(mx, __shfl_xor(mx, 4)); mx = fmaxf(mx, __shfl_xor(mx, 8));
      float sum = 0.f;
#pragma unroll
      for (int nt = 0; nt < 4; nt++) { sv[nt] = __expf(sv[nt] - mx); sum += sv[nt]; }
      sum += __shfl_xor(sum, 1); sum += __shfl_xor(sum, 2);
      sum += __shfl_xor(sum, 4); sum += __shfl_xor(sum, 8);
      float inv = 1.f / sum;
#pragma unroll
      for (int nt = 0; nt < 4; nt++) ps[rr * VTS + nt * 16 + lr] = (__bf16)(sv[nt] * inv);
    }
    asm volatile("s_waitcnt lgkmcnt(0)" ::: "memory");
#pragma unroll
    for (int dt = 0; dt < 2; dt++) {
      f32x4 acc = {0.f, 0.f, 0.f, 0.f};
#pragma unroll
      for (int kk = 0; kk < 2; kk++) {
        bf16x8 ap = *(const bf16x8*)(ps + (r0 + lr) * VTS + kk * 32 + lk * 8);
        bf16x8 bv2 = *(const bf16x8*)(vt + (h * 32 + dt * 16 + lr) * VTS + kk * 32 + lk * 8);
        acc = MFMA16(ap, bv2, acc);
      }
      int d = h * 32 + dt * 16 + lr;
#pragma unroll
      for (int i = 0; i < 4; i++) xn[(r0 + lk * 4 + i) * XS + d] = (__bf16)acc[i];
    }
    asm volatile("s_waitcnt lgkmcnt(0)" ::: "memory");
  }
  __syncthreads();

  // ---- Phase D: proj col-slice (wave owns 32 cols) + residual, inverse roll ----
  {
#pragma unroll
    for (int st = 0; st < 4; st++) {
      bf16x8 ao[4];
#pragma unroll
      for (int kk = 0; kk < 4; kk++)
        ao[kk] = *(const bf16x8*)(xn + (st * 16 + lr) * XS + kk * 32 + lk * 8);
      size_t gids[4];
#pragma unroll
      for (int i = 0; i < 4; i++) {
        int rr = st * 16 + lk * 4 + i;
        int io = (wi * 8 + (rr >> 3) + SS) & 511;
        int jo = (wj * 8 + (rr & 7) + SS) & 511;
        gids[i] = (size_t)io * 512 + jo;
      }
#pragma unroll
      for (int nt2 = 0; nt2 < 2; nt2++) {
        f32x4 acc = {0.f, 0.f, 0.f, 0.f};
#pragma unroll
        for (int kk = 0; kk < 4; kk++) acc = MFMA16(ao[kk], pwf[nt2][kk], acc);
        int j = wid * 32 + nt2 * 16 + lr;
#pragma unroll
        for (int i = 0; i < 4; i++) {
          size_t off = gids[i] * 128 + j;
          out[off] = x[off] + acc[i] + pb2[nt2];
        }
      }
    }
  }
}

__device__ __forceinline__ float gelu_fast(float x) {
  // tanh-gelu via v_exp + v_rcp: tanh(t) = 1 - 2/(exp(2t)+1)
  float u = 0.7978845608028654f * x * (1.f + 0.044715f * x * x);
  float e = __expf(2.f * u);
  float th = 1.f - 2.f * __builtin_amdgcn_rcpf(e + 1.f);
  return 0.5f * x * (1.f + th);
}

__global__ __launch_bounds__(512, 1) void mlp_kernel(
    const float* __restrict__ ln2_w, const float* __restrict__ ln2_b,
    const float* __restrict__ mlp_b1, const float* __restrict__ mlp_b2,
    const unsigned char* __restrict__ ws, float* __restrict__ out) {
  __shared__ __attribute__((aligned(16))) __bf16 xn[64 * 128];  // LN2 out, XOR-swizzled
  __shared__ __attribute__((aligned(16))) __bf16 hb[64 * 512];  // gelu(h), XOR-swizzled
  const int tid = threadIdx.x;
  const int wid = tid >> 6, lane = tid & 63;
  const int lr = lane & 15, lk = lane >> 4;

  // ---- weights: register-resident, loaded once (coalesced frag-order) ----
  const __bf16* w1r = (const __bf16*)(ws + W1_OFF);
  const __bf16* w2r = (const __bf16*)(ws + W2_OFF);
  bf16x8 w1f[4][4], w2f[16];
#pragma unroll
  for (int nt = 0; nt < 4; nt++)
#pragma unroll
    for (int kk = 0; kk < 4; kk++)
      w1f[nt][kk] = *(const bf16x8*)(w1r + ((wid * 4 + nt) * 4 + kk) * 512 + lane * 8);
#pragma unroll
  for (int kk = 0; kk < 16; kk++)
    w2f[kk] = *(const bf16x8*)(w2r + (wid * 16 + kk) * 512 + lane * 8);
  float b1v[4];
#pragma unroll
  for (int nt = 0; nt < 4; nt++) b1v[nt] = mlp_b1[wid * 64 + nt * 16 + lr];
  float b2v = mlp_b2[wid * 16 + lr];

  for (int tt = 0; tt < 4; tt++) {
    const int row0 = (blockIdx.x * 4 + tt) * 64;

    // ---- LN2: 8 threads/row, 16 elems each ----
    {
      int n = tid >> 3, q = tid & 7;
      const float4* xp = (const float4*)(out + (size_t)(row0 + n) * 128 + q * 16);
      float4 xv[4];
      float s = 0.f, s2 = 0.f;
#pragma unroll
      for (int t = 0; t < 4; t++) {
        float4 v = xp[t]; xv[t] = v;
        s += v.x + v.y + v.z + v.w;
        s2 += v.x * v.x + v.y * v.y + v.z * v.z + v.w * v.w;
      }
      s += __shfl_xor(s, 1); s += __shfl_xor(s, 2); s += __shfl_xor(s, 4);
      s2 += __shfl_xor(s2, 1); s2 += __shfl_xor(s2, 2); s2 += __shfl_xor(s2, 4);
      float mean = s * (1.f / 128.f);
      float var = s2 * (1.f / 128.f) - mean * mean;
      float rstd = rsqrtf(var + 1e-5f);
      const float4* wv = (const float4*)(ln2_w + q * 16);
      const float4* bv = (const float4*)(ln2_b + q * 16);
      bf16x8 o[2];
#pragma unroll
      for (int t = 0; t < 4; t++) {
        float4 wt = wv[t], bt = bv[t], v = xv[t];
        o[t >> 1][(t & 1) * 4 + 0] = (__bf16)((v.x - mean) * rstd * wt.x + bt.x);
        o[t >> 1][(t & 1) * 4 + 1] = (__bf16)((v.y - mean) * rstd * wt.y + bt.y);
        o[t >> 1][(t & 1) * 4 + 2] = (__bf16)((v.z - mean) * rstd * wt.z + bt.z);
        o[t >> 1][(t & 1) * 4 + 3] = (__bf16)((v.w - mean) * rstd * wt.w + bt.w);
      }
      *(bf16x8*)(xn + n * 128 + (((q * 2 + 0) ^ (n & 15)) << 3)) = o[0];
      *(bf16x8*)(xn + n * 128 + (((q * 2 + 1) ^ (n & 15)) << 3)) = o[1];
    }
    __syncthreads();

    // ---- fc1 + gelu -> hb (wave owns 64 hidden cols) ----
#pragma unroll 1
    for (int st = 0; st < 4; st++) {
      bf16x8 a1[4];
#pragma unroll
      for (int kk = 0; kk < 4; kk++)
        a1[kk] = *(const bf16x8*)(xn + (st * 16 + lr) * 128 + (((kk * 4 + lk) ^ lr) << 3));
#pragma unroll
      for (int nt = 0; nt < 4; nt++) {
        f32x4 acc = {0.f, 0.f, 0.f, 0.f};
#pragma unroll
        for (int kk = 0; kk < 4; kk++) acc = MFMA16(a1[kk], w1f[nt][kk], acc);
        int slot = wid * 8 + nt * 2 + (lr >> 3);
#pragma unroll
        for (int i = 0; i < 4; i++) {
          int row = st * 16 + lk * 4 + i;
          hb[row * 512 + ((slot ^ (row & 15)) << 3) + (lr & 7)] =
              (__bf16)gelu_fast(acc[i] + b1v[nt]);
        }
      }
    }
    __syncthreads();

    // ---- fc2 (wave owns 16 out cols, K=512 in regs) + residual epilogue ----
#pragma unroll 1
    for (int st = 0; st < 4; st++) {
      bf16x8 ah[16];
#pragma unroll
      for (int kk = 0; kk < 16; kk++)
        ah[kk] = *(const bf16x8*)(hb + (st * 16 + lr) * 512 + (((kk * 4 + lk) ^ lr) << 3));
      f32x4 acc0 = {0.f, 0.f, 0.f, 0.f}, acc1 = {0.f, 0.f, 0.f, 0.f};
#pragma unroll
      for (int kk = 0; kk < 8; kk++) {
        acc0 = MFMA16(ah[kk], w2f[kk], acc0);
        acc1 = MFMA16(ah[kk + 8], w2f[kk + 8], acc1);
      }
#pragma unroll
      for (int i = 0; i < 4; i++) {
        size_t off = (size_t)(row0 + st * 16 + lk * 4 + i) * 128 + wid * 16 + lr;
        out[off] = out[off] + acc0[i] + acc1[i] + b2v;
      }
    }
    // no end-of-tile barrier needed: next LN writes xn (readers done pre-B2),
    // next fc1 writes hb only after next B1 (all waves past this fc2).
  }
}

extern "C" void kernel_launch(void* const* d_in, const int* in_sizes, int n_in,
                              void* d_out, int out_size, void* d_ws, size_t ws_size,
                              hipStream_t stream) {
  const float* x      = (const float*)d_in[0];
  const float* ln1_w  = (const float*)d_in[1];
  const float* ln1_b  = (const float*)d_in[2];
  const float* qkv_w  = (const float*)d_in[3];
  const float* qkv_b  = (const float*)d_in[4];
  const float* rel_b  = (const float*)d_in[5];
  const float* proj_w = (const float*)d_in[6];
  const float* proj_b = (const float*)d_in[7];
  const float* ln2_w  = (const float*)d_in[8];
  const float* ln2_b  = (const float*)d_in[9];
  const float* mlp_w1 = (const float*)d_in[10];
  const float* mlp_b1 = (const float*)d_in[11];
  const float* mlp_w2 = (const float*)d_in[12];
  const float* mlp_b2 = (const float*)d_in[13];
  float* out = (float*)d_out;
  unsigned char* ws = (unsigned char*)d_ws;

  prep_kernel<<<256, 256, 0, stream>>>(qkv_w, proj_w, mlp_w1, mlp_w2, rel_b, ws);
  attn_kernel<<<4096, 256, 0, stream>>>(x, ln1_w, ln1_b, qkv_b, proj_b, ws, out);
  mlp_kernel<<<1024, 512, 0, stream>>>(ln2_w, ln2_b, mlp_b1, mlp_b2, ws, out);
}

// Round 5
// 260.643 us; speedup vs baseline: 3.2212x; 1.1756x over previous
//
#include <hip/hip_runtime.h>
#include <hip/hip_bf16.h>

// FBANetLayer: Swin-style block. H=W=512, DIM=128, WL=8, SS=4, HEADS=4, HD=32.
// attn: head-per-wave. Wave h computes QKV_h (col-slice via frag-order weights),
//       stages q/k/vt in wave-private LDS, scores via SWAPPED mfma (S^T=K*Q^T)
//       with rel-pos bias as MFMA C-init, max-free softmax (2 shfl), PV, O to
//       wave-private LDS. Only 2 barriers: after LN, before proj.
// mlp:  1024 blocks x 4 row-tiles(64), weights register-resident per wave.

typedef __bf16 bf16x8 __attribute__((ext_vector_type(8)));
typedef __bf16 bf16x2 __attribute__((ext_vector_type(2)));
typedef float f32x4 __attribute__((ext_vector_type(4)));

#define MFMA16(a, b, c) __builtin_amdgcn_mfma_f32_16x16x32_bf16(a, b, c, 0, 0, 0)

#define SS 4
#define XS 136   // attn LDS stride (bf16) for the 128-wide xn tile (2-way banks)
#define QKS 40   // stride for 32-wide q/k/O tiles (2-way banks)
#define PSS 72   // stride for 64-wide ps / vt tiles (2-way banks)

// ws byte offsets (total 458,752 B)
#define QKV_W_OFF 0        // 384x128 bf16 frag-order: ((h*6+nt)*4+kk)*512 + lane*8
                           //   j = (nt>>1)*128 + h*32 + (nt&1)*16 + (lane&15)
#define PROJ_W_OFF 98304   // 128x128 bf16 frag-order: ((wid*2+nt2)*4+kk)*512 + lane*8
#define W1_OFF 131072      // 512x128 bf16 frag-order (mlp fc1)
#define W2_OFF 262144      // 128x512 bf16 frag-order (mlp fc2)
#define BIAS_OFF 393216    // bias C-frag table: f32[((h*4+qt)*4+kt)*256 + lane*4 + i]

__device__ __forceinline__ int regid(int u) { return (u >= 508) ? 2 : ((u >= 504) ? 1 : 0); }

__global__ __launch_bounds__(256) void prep_kernel(
    const float* __restrict__ qkv_w, const float* __restrict__ proj_w,
    const float* __restrict__ w1, const float* __restrict__ w2,
    const float* __restrict__ rel_bias, unsigned char* __restrict__ ws) {
  int tid = blockIdx.x * 256 + threadIdx.x;
  __bf16* qw = (__bf16*)(ws + QKV_W_OFF);
  __bf16* pw = (__bf16*)(ws + PROJ_W_OFF);
  __bf16* w1b = (__bf16*)(ws + W1_OFF);
  __bf16* w2b = (__bf16*)(ws + W2_OFF);
  float* btbl = (float*)(ws + BIAS_OFF);
  if (tid < 49152) {
    int e = tid & 7, lane = (tid >> 3) & 63, kk = (tid >> 9) & 3;
    int f = tid >> 11;            // 0..23 = h*6+nt
    int h = f / 6, nt = f % 6;
    int j = (nt >> 1) * 128 + h * 32 + (nt & 1) * 16 + (lane & 15);
    int k = kk * 32 + (lane >> 4) * 8 + e;
    qw[tid] = (__bf16)qkv_w[j * 128 + k];
  }
  if (tid < 16384) {
    int e = tid & 7, lane = (tid >> 3) & 63, kk = (tid >> 9) & 3;
    int nt2 = (tid >> 11) & 1, wid = (tid >> 12) & 3;
    int j = wid * 32 + nt2 * 16 + (lane & 15);
    int k = kk * 32 + (lane >> 4) * 8 + e;
    pw[tid] = (__bf16)proj_w[j * 128 + k];
  }
  if (tid < 65536) {
    { int e = tid & 7, lane = (tid >> 3) & 63, kk = (tid >> 9) & 3;
      int nt = (tid >> 11) & 3, wid = (tid >> 13) & 7;
      int j = wid * 64 + nt * 16 + (lane & 15);
      int k = kk * 32 + (lane >> 4) * 8 + e;
      w1b[tid] = (__bf16)w1[j * 128 + k]; }
    { int e = tid & 7, lane = (tid >> 3) & 63, kk = (tid >> 9) & 15, wid = (tid >> 13) & 7;
      int j = wid * 16 + (lane & 15);
      int k = kk * 32 + (lane >> 4) * 8 + e;
      w2b[tid] = (__bf16)w2[j * 512 + k]; }
  }
  if (tid < 16384) {
    // bias C-frag table: lane holds C[row=k-tok=(l>>4)*4+i][col=q-tok=l&15]
    int i = tid & 3, lane = (tid >> 2) & 63;
    int kt = (tid >> 8) & 3, qt = (tid >> 10) & 3, h = (tid >> 12) & 3;
    int n = qt * 16 + (lane & 15);          // q token
    int m = kt * 16 + (lane >> 4) * 4 + i;  // k token
    int idx = ((n >> 3) - (m >> 3) + 7) * 15 + ((n & 7) - (m & 7) + 7);
    btbl[tid] = rel_bias[idx * 4 + h];
  }
}

__global__ __launch_bounds__(256, 2) void attn_kernel(
    const float* __restrict__ x, const float* __restrict__ ln1_w, const float* __restrict__ ln1_b,
    const float* __restrict__ qkv_b, const float* __restrict__ proj_b,
    const unsigned char* __restrict__ ws, float* __restrict__ out) {
  // wave-private regions: wreg[w] holds q(0..2559)+k(2560..5119), later ps
  // (stripes of 16x72 per qt), later O (within each qt stripe). vt[w] = V^T.
  __shared__ __attribute__((aligned(16))) __bf16 xn[64 * XS];   // 17,408 B
  __shared__ __attribute__((aligned(16))) __bf16 wreg[4][5120]; // 4 x 10,240 B
  __shared__ __attribute__((aligned(16))) __bf16 vt[4][32 * PSS]; // 4 x 4,608 B
  __shared__ __attribute__((aligned(16))) int rid[64];

  const int w = blockIdx.x;
  const int wi = w >> 6, wj = w & 63;
  const int tid = threadIdx.x;
  const int wid = tid >> 6, lane = tid & 63;
  const int lr = lane & 15, lk = lane >> 4;
  const bool edge = (wi == 63) || (wj == 63);
  const f32x4 zero4 = {0.f, 0.f, 0.f, 0.f};

  // ---- Hoisted QKV B-frags: wave wid's head slice {Q_h,K_h,V_h} ----
  const __bf16* qw = (const __bf16*)(ws + QKV_W_OFF);
  bf16x8 bw[6][4];
  float qb[6];
#pragma unroll
  for (int nt = 0; nt < 6; nt++) {
    qb[nt] = qkv_b[(nt >> 1) * 128 + wid * 32 + (nt & 1) * 16 + lr];
#pragma unroll
    for (int kk = 0; kk < 4; kk++)
      bw[nt][kk] = *(const bf16x8*)(qw + ((wid * 6 + nt) * 4 + kk) * 512 + lane * 8);
  }

  // ---- Phase A: gather rolled rows + LN1 -> bf16 LDS ----
  {
    int n = tid >> 2, q = tid & 3;
    int r = n >> 3, c = n & 7;
    int io = (wi * 8 + r + SS) & 511;
    int jo = (wj * 8 + c + SS) & 511;
    size_t gid = (size_t)io * 512 + jo;
    const float4* xp = (const float4*)(x + gid * 128 + q * 32);
    float4 xv[8];
    float s = 0.f, s2 = 0.f;
#pragma unroll
    for (int t = 0; t < 8; t++) {
      float4 v = xp[t]; xv[t] = v;
      s += v.x + v.y + v.z + v.w;
      s2 += v.x * v.x + v.y * v.y + v.z * v.z + v.w * v.w;
    }
    s += __shfl_xor(s, 1); s += __shfl_xor(s, 2);
    s2 += __shfl_xor(s2, 1); s2 += __shfl_xor(s2, 2);
    float mean = s * (1.f / 128.f);
    float var = s2 * (1.f / 128.f) - mean * mean;
    float rstd = rsqrtf(var + 1e-5f);
    const float4* wv = (const float4*)(ln1_w + q * 32);
    const float4* bv = (const float4*)(ln1_b + q * 32);
    __bf16* dst = xn + n * XS + q * 32;
#pragma unroll
    for (int t = 0; t < 8; t++) {
      float4 wt = wv[t], bt = bv[t], v = xv[t];
      dst[t * 4 + 0] = (__bf16)((v.x - mean) * rstd * wt.x + bt.x);
      dst[t * 4 + 1] = (__bf16)((v.y - mean) * rstd * wt.y + bt.y);
      dst[t * 4 + 2] = (__bf16)((v.z - mean) * rstd * wt.z + bt.z);
      dst[t * 4 + 3] = (__bf16)((v.w - mean) * rstd * wt.w + bt.w);
    }
    if (q == 0) rid[n] = 3 * regid(wi * 8 + r) + regid(wj * 8 + c);
  }
  __syncthreads();

  // ---- Phase B: QKV for head wid (64 rows x 96 cols), into private LDS ----
  {
    const float scale = 0.17677669529663687f;  // 32^-0.5 folded into Q
    __bf16* qbase = &wreg[wid][0];
    __bf16* kbase = &wreg[wid][2560];
    __bf16* vbase = &vt[wid][0];
#pragma unroll
    for (int st = 0; st < 4; st++) {
      bf16x8 a[4];
#pragma unroll
      for (int kk = 0; kk < 4; kk++)
        a[kk] = *(const bf16x8*)(xn + (st * 16 + lr) * XS + kk * 32 + lk * 8);
#pragma unroll
      for (int nt = 0; nt < 6; nt++) {
        f32x4 acc = zero4;
#pragma unroll
        for (int kk = 0; kk < 4; kk++) acc = MFMA16(a[kk], bw[nt][kk], acc);
        float bias = qb[nt];
        int dl = (nt & 1) * 16 + lr;           // d_local within head
        if (nt < 2) {
#pragma unroll
          for (int i = 0; i < 4; i++)
            qbase[(st * 16 + lk * 4 + i) * QKS + dl] = (__bf16)((acc[i] + bias) * scale);
        } else if (nt < 4) {
#pragma unroll
          for (int i = 0; i < 4; i++)
            kbase[(st * 16 + lk * 4 + i) * QKS + dl] = (__bf16)(acc[i] + bias);
        } else {
#pragma unroll
          for (int i = 0; i < 4; i++)
            vbase[dl * PSS + st * 16 + lk * 4 + i] = (__bf16)(acc[i] + bias);
        }
      }
    }
  }

  // ---- hoist proj B-frags + bias C-frags (loads overlap frag staging) ----
  const __bf16* pw = (const __bf16*)(ws + PROJ_W_OFF);
  bf16x8 pwf[2][4];
  float pb2[2];
#pragma unroll
  for (int nt2 = 0; nt2 < 2; nt2++) {
    pb2[nt2] = proj_b[wid * 32 + nt2 * 16 + lr];
#pragma unroll
    for (int kk = 0; kk < 4; kk++)
      pwf[nt2][kk] = *(const bf16x8*)(pw + ((wid * 2 + nt2) * 4 + kk) * 512 + lane * 8);
  }
  const float* btbl = (const float*)(ws + BIAS_OFF);
  f32x4 bc[4][4];
#pragma unroll
  for (int qt = 0; qt < 4; qt++)
#pragma unroll
    for (int kt = 0; kt < 4; kt++)
      bc[qt][kt] = *(const f32x4*)(btbl + ((wid * 4 + qt) * 4 + kt) * 256 + lane * 4);

  // ---- Phase C: head-private attention (no barriers) ----
  {
    __bf16* reg0 = &wreg[wid][0];
    // load all q/k/vt frags, then region is reusable for ps/O
    bf16x8 kf[4], qf[4], vf[2][2];
#pragma unroll
    for (int kt = 0; kt < 4; kt++)
      kf[kt] = *(const bf16x8*)(reg0 + 2560 + (kt * 16 + lr) * QKS + lk * 8);
#pragma unroll
    for (int qt = 0; qt < 4; qt++)
      qf[qt] = *(const bf16x8*)(reg0 + (qt * 16 + lr) * QKS + lk * 8);
#pragma unroll
    for (int dt = 0; dt < 2; dt++)
#pragma unroll
      for (int kk = 0; kk < 2; kk++)
        vf[dt][kk] = *(const bf16x8*)(&vt[wid][(dt * 16 + lr) * PSS + kk * 32 + lk * 8]);
    // ensure frag reads retired before overwriting region with ps
    asm volatile("s_waitcnt lgkmcnt(0)" ::: "memory");
    __builtin_amdgcn_sched_barrier(0);

    int4 rk[4];
    if (edge) {
#pragma unroll
      for (int kt = 0; kt < 4; kt++) rk[kt] = *(const int4*)&rid[kt * 16 + lk * 4];
    }

#pragma unroll
    for (int qt = 0; qt < 4; qt++) {
      // S^T tiles: lane holds S[q = qt*16+lr][k = kt*16+lk*4+i], bias pre-added
      f32x4 s[4];
#pragma unroll
      for (int kt = 0; kt < 4; kt++) s[kt] = MFMA16(kf[kt], qf[qt], bc[qt][kt]);
      if (edge) {
        int rq = rid[qt * 16 + lr];
#pragma unroll
        for (int kt = 0; kt < 4; kt++) {
          s[kt][0] += (rk[kt].x != rq) ? -100.f : 0.f;
          s[kt][1] += (rk[kt].y != rq) ? -100.f : 0.f;
          s[kt][2] += (rk[kt].z != rq) ? -100.f : 0.f;
          s[kt][3] += (rk[kt].w != rq) ? -100.f : 0.f;
        }
      }
      // max-free softmax: scores tiny (|qk|~0.1, mask -100) -> exp safe
      float ex[4][4];
      float sum = 0.f;
#pragma unroll
      for (int kt = 0; kt < 4; kt++) {
#pragma unroll
        for (int i = 0; i < 4; i++) { ex[kt][i] = __expf(s[kt][i]); sum += ex[kt][i]; }
      }
      sum += __shfl_xor(sum, 16);
      sum += __shfl_xor(sum, 32);
      float inv = __builtin_amdgcn_rcpf(sum);
      // write P row-major into ps (overlay of q/k region)
      __bf16* psrow = reg0 + (qt * 16 + lr) * PSS;
#pragma unroll
      for (int kt = 0; kt < 4; kt++) {
        bf16x2 p01 = {(__bf16)(ex[kt][0] * inv), (__bf16)(ex[kt][1] * inv)};
        bf16x2 p23 = {(__bf16)(ex[kt][2] * inv), (__bf16)(ex[kt][3] * inv)};
        *(bf16x2*)(psrow + kt * 16 + lk * 4) = p01;
        *(bf16x2*)(psrow + kt * 16 + lk * 4 + 2) = p23;
      }
      // PV for this qt: O[qt*16+.., 32 dims]
#pragma unroll
      for (int dt = 0; dt < 2; dt++) {
        bf16x8 pa0 = *(const bf16x8*)(reg0 + (qt * 16 + lr) * PSS + lk * 8);
        bf16x8 pa1 = *(const bf16x8*)(reg0 + (qt * 16 + lr) * PSS + 32 + lk * 8);
        f32x4 acc = MFMA16(pa0, vf[dt][0], zero4);
        acc = MFMA16(pa1, vf[dt][1], acc);
        // O into dead ps stripe qt: stripe base qt*1152, token-major stride QKS
#pragma unroll
        for (int i = 0; i < 4; i++)
          reg0[qt * 1152 + (lk * 4 + i) * QKS + dt * 16 + lr] = (__bf16)acc[i];
      }
    }
  }
  __syncthreads();

  // ---- Phase D: proj col-slice (wave owns 32 cols) + residual, inverse roll ----
  {
#pragma unroll
    for (int st = 0; st < 4; st++) {
      bf16x8 ao[4];
#pragma unroll
      for (int kk = 0; kk < 4; kk++)   // head kk's O stripe st
        ao[kk] = *(const bf16x8*)(&wreg[kk][st * 1152 + lr * QKS + lk * 8]);
      size_t gids[4];
#pragma unroll
      for (int i = 0; i < 4; i++) {
        int rr = st * 16 + lk * 4 + i;
        int io = (wi * 8 + (rr >> 3) + SS) & 511;
        int jo = (wj * 8 + (rr & 7) + SS) & 511;
        gids[i] = (size_t)io * 512 + jo;
      }
#pragma unroll
      for (int nt2 = 0; nt2 < 2; nt2++) {
        f32x4 acc = zero4;
#pragma unroll
        for (int kk = 0; kk < 4; kk++) acc = MFMA16(ao[kk], pwf[nt2][kk], acc);
        int j = wid * 32 + nt2 * 16 + lr;
#pragma unroll
        for (int i = 0; i < 4; i++) {
          size_t off = gids[i] * 128 + j;
          out[off] = x[off] + acc[i] + pb2[nt2];
        }
      }
    }
  }
}

__device__ __forceinline__ float gelu_fast(float x) {
  float u = 0.7978845608028654f * x * (1.f + 0.044715f * x * x);
  float e = __expf(2.f * u);
  float th = 1.f - 2.f * __builtin_amdgcn_rcpf(e + 1.f);
  return 0.5f * x * (1.f + th);
}

__global__ __launch_bounds__(512, 1) void mlp_kernel(
    const float* __restrict__ ln2_w, const float* __restrict__ ln2_b,
    const float* __restrict__ mlp_b1, const float* __restrict__ mlp_b2,
    const unsigned char* __restrict__ ws, float* __restrict__ out) {
  __shared__ __attribute__((aligned(16))) __bf16 xn[64 * 128];  // LN2 out, XOR-swizzled
  __shared__ __attribute__((aligned(16))) __bf16 hb[64 * 512];  // gelu(h), XOR-swizzled
  const int tid = threadIdx.x;
  const int wid = tid >> 6, lane = tid & 63;
  const int lr = lane & 15, lk = lane >> 4;
  const f32x4 zero4 = {0.f, 0.f, 0.f, 0.f};

  const __bf16* w1r = (const __bf16*)(ws + W1_OFF);
  const __bf16* w2r = (const __bf16*)(ws + W2_OFF);
  bf16x8 w1f[4][4], w2f[16];
#pragma unroll
  for (int nt = 0; nt < 4; nt++)
#pragma unroll
    for (int kk = 0; kk < 4; kk++)
      w1f[nt][kk] = *(const bf16x8*)(w1r + ((wid * 4 + nt) * 4 + kk) * 512 + lane * 8);
#pragma unroll
  for (int kk = 0; kk < 16; kk++)
    w2f[kk] = *(const bf16x8*)(w2r + (wid * 16 + kk) * 512 + lane * 8);
  float b1v[4];
#pragma unroll
  for (int nt = 0; nt < 4; nt++) b1v[nt] = mlp_b1[wid * 64 + nt * 16 + lr];
  float b2v = mlp_b2[wid * 16 + lr];

  for (int tt = 0; tt < 4; tt++) {
    const int row0 = (blockIdx.x * 4 + tt) * 64;

    {
      int n = tid >> 3, q = tid & 7;
      const float4* xp = (const float4*)(out + (size_t)(row0 + n) * 128 + q * 16);
      float4 xv[4];
      float s = 0.f, s2 = 0.f;
#pragma unroll
      for (int t = 0; t < 4; t++) {
        float4 v = xp[t]; xv[t] = v;
        s += v.x + v.y + v.z + v.w;
        s2 += v.x * v.x + v.y * v.y + v.z * v.z + v.w * v.w;
      }
      s += __shfl_xor(s, 1); s += __shfl_xor(s, 2); s += __shfl_xor(s, 4);
      s2 += __shfl_xor(s2, 1); s2 += __shfl_xor(s2, 2); s2 += __shfl_xor(s2, 4);
      float mean = s * (1.f / 128.f);
      float var = s2 * (1.f / 128.f) - mean * mean;
      float rstd = rsqrtf(var + 1e-5f);
      const float4* wv = (const float4*)(ln2_w + q * 16);
      const float4* bv = (const float4*)(ln2_b + q * 16);
      bf16x8 o[2];
#pragma unroll
      for (int t = 0; t < 4; t++) {
        float4 wt = wv[t], bt = bv[t], v = xv[t];
        o[t >> 1][(t & 1) * 4 + 0] = (__bf16)((v.x - mean) * rstd * wt.x + bt.x);
        o[t >> 1][(t & 1) * 4 + 1] = (__bf16)((v.y - mean) * rstd * wt.y + bt.y);
        o[t >> 1][(t & 1) * 4 + 2] = (__bf16)((v.z - mean) * rstd * wt.z + bt.z);
        o[t >> 1][(t & 1) * 4 + 3] = (__bf16)((v.w - mean) * rstd * wt.w + bt.w);
      }
      *(bf16x8*)(xn + n * 128 + (((q * 2 + 0) ^ (n & 15)) << 3)) = o[0];
      *(bf16x8*)(xn + n * 128 + (((q * 2 + 1) ^ (n & 15)) << 3)) = o[1];
    }
    __syncthreads();

#pragma unroll 1
    for (int st = 0; st < 4; st++) {
      bf16x8 a1[4];
#pragma unroll
      for (int kk = 0; kk < 4; kk++)
        a1[kk] = *(const bf16x8*)(xn + (st * 16 + lr) * 128 + (((kk * 4 + lk) ^ lr) << 3));
#pragma unroll
      for (int nt = 0; nt < 4; nt++) {
        f32x4 acc = zero4;
#pragma unroll
        for (int kk = 0; kk < 4; kk++) acc = MFMA16(a1[kk], w1f[nt][kk], acc);
        int slot = wid * 8 + nt * 2 + (lr >> 3);
#pragma unroll
        for (int i = 0; i < 4; i++) {
          int row = st * 16 + lk * 4 + i;
          hb[row * 512 + ((slot ^ (row & 15)) << 3) + (lr & 7)] =
              (__bf16)gelu_fast(acc[i] + b1v[nt]);
        }
      }
    }
    __syncthreads();

#pragma unroll 1
    for (int st = 0; st < 4; st++) {
      bf16x8 ah[16];
#pragma unroll
      for (int kk = 0; kk < 16; kk++)
        ah[kk] = *(const bf16x8*)(hb + (st * 16 + lr) * 512 + (((kk * 4 + lk) ^ lr) << 3));
      f32x4 acc0 = zero4, acc1 = zero4;
#pragma unroll
      for (int kk = 0; kk < 8; kk++) {
        acc0 = MFMA16(ah[kk], w2f[kk], acc0);
        acc1 = MFMA16(ah[kk + 8], w2f[kk + 8], acc1);
      }
#pragma unroll
      for (int i = 0; i < 4; i++) {
        size_t off = (size_t)(row0 + st * 16 + lk * 4 + i) * 128 + wid * 16 + lr;
        out[off] = out[off] + acc0[i] + acc1[i] + b2v;
      }
    }
  }
}

extern "C" void kernel_launch(void* const* d_in, const int* in_sizes, int n_in,
                              void* d_out, int out_size, void* d_ws, size_t ws_size,
                              hipStream_t stream) {
  const float* x      = (const float*)d_in[0];
  const float* ln1_w  = (const float*)d_in[1];
  const float* ln1_b  = (const float*)d_in[2];
  const float* qkv_w  = (const float*)d_in[3];
  const float* qkv_b  = (const float*)d_in[4];
  const float* rel_b  = (const float*)d_in[5];
  const float* proj_w = (const float*)d_in[6];
  const float* proj_b = (const float*)d_in[7];
  const float* ln2_w  = (const float*)d_in[8];
  const float* ln2_b  = (const float*)d_in[9];
  const float* mlp_w1 = (const float*)d_in[10];
  const float* mlp_b1 = (const float*)d_in[11];
  const float* mlp_w2 = (const float*)d_in[12];
  const float* mlp_b2 = (const float*)d_in[13];
  float* out = (float*)d_out;
  unsigned char* ws = (unsigned char*)d_ws;

  prep_kernel<<<256, 256, 0, stream>>>(qkv_w, proj_w, mlp_w1, mlp_w2, rel_b, ws);
  attn_kernel<<<4096, 256, 0, stream>>>(x, ln1_w, ln1_b, qkv_b, proj_b, ws, out);
  mlp_kernel<<<1024, 512, 0, stream>>>(ln2_w, ln2_b, mlp_b1, mlp_b2, ws, out);
}